// Round 9
// baseline (3912.886 us; speedup 1.0000x reference)
//
#include <hip/hip_runtime.h>
#include <hip/hip_bf16.h>

typedef __hip_bfloat16 bf16;

#define N_NODES 100000
#define N_EDGES 400000

// ---- byte/element offsets inside d_out ----
#define OUT_E_ELEM   ((size_t)N_NODES*128)            // element offset of out_e
#define SCORES_B     ((size_t)N_EDGES*8*4)            // 12.8 MB
#define SEG_B        ((size_t)N_NODES*8*4)            //  3.2 MB
#define AGG_OFF_BF16 ((size_t)N_NODES*128*2)          // 25.6 MB (start of out_e, bf16)
#define AGG_OFF_F32  ((size_t)N_NODES*128*4)          // 51.2 MB (start of out_e, f32)
#define AGG_BYTES    ((size_t)N_NODES*128*4)          // 51.2 MB

__device__ __forceinline__ float b2f(bf16 v){ return __bfloat162float(v); }
__device__ __forceinline__ bf16  f2b(float v){ return __float2bfloat16(v); }

__device__ __forceinline__ float ldIn(const void* p, size_t i, int f32){
  return f32 ? ((const float*)p)[i] : b2f(((const bf16*)p)[i]);
}
__device__ __forceinline__ void stOut(void* p, size_t i, float v, int f32){
  if (f32) ((float*)p)[i] = v; else ((bf16*)p)[i] = f2b(v);
}
// NaN/Inf scrub: guarantees finite outputs (diagnostic; no-op when math is healthy)
__device__ __forceinline__ float san(float v){
  return (v == v && fabsf(v) < 1e30f) ? v : 0.f;
}

// order-preserving float->uint map for atomicMax-based float max
__device__ __forceinline__ unsigned fmap(float f){
  unsigned u = __float_as_uint(f);
  return (u & 0x80000000u) ? ~u : (u | 0x80000000u);
}
__device__ __forceinline__ float funmap(unsigned u){
  unsigned b = (u & 0x80000000u) ? (u ^ 0x80000000u) : ~u;
  return __uint_as_float(b);
}

// ---- dtype detector: W_Q is uniform(-0.088,0.088). Read 256 bf16s; if the
// buffer is actually f32, ~50% of low-mantissa halves decode to |v|>1 or NaN.
__global__ void detect_dtype(const void* w, int* flag){
  __shared__ int cnt;
  if (threadIdx.x == 0) cnt = 0;
  __syncthreads();
  const bf16* p = (const bf16*)w;
  int c = 0;
  for (int i = threadIdx.x; i < 256; i += 64){
    float v = b2f(p[i]);
    if (!(v == v) || fabsf(v) > 1.0f) c++;
  }
  atomicAdd(&cnt, c);
  __syncthreads();
  if (threadIdx.x == 0) *flag = (cnt > 32) ? 1 : 0;
}

// ---- edge front-end: per 16-edge block, fused GEMVs Q[src],K[tgt],Ew,Eb ->
// attn_feat (LDS only) -> scores + segmax. No big intermediates stored.
__global__ __launch_bounds__(256) void edge_score(
    const void* __restrict__ x, const void* __restrict__ ea,
    const int* __restrict__ eidx,
    const void* __restrict__ W_Q, const void* __restrict__ b_Q,
    const void* __restrict__ W_K, const void* __restrict__ b_K,
    const void* __restrict__ W_Ew, const void* __restrict__ b_Ew,
    const void* __restrict__ W_Eb, const void* __restrict__ b_Eb,
    const void* __restrict__ W_A,  const void* __restrict__ b_A,
    float* __restrict__ scores, unsigned* __restrict__ segmax,
    const int* __restrict__ flagp)
{
  const int f32 = *flagp;
  __shared__ float eaT[128][16], xsT[128][16], xtT[128][16];
  __shared__ float afL[16][132];
  __shared__ int sIdx[16], tIdx[16];

  const int tid = threadIdx.x;
  const int e0  = blockIdx.x * 16;

  if (tid < 16){
    sIdx[tid] = eidx[e0 + tid];
    tIdx[tid] = eidx[N_EDGES + e0 + tid];
  }
  __syncthreads();                     // indices needed for the gathers below

  for (int idx = tid; idx < 16*128; idx += 256){
    int r = idx >> 7, k = idx & 127;
    eaT[k][r] = ldIn(ea, (size_t)(e0 + r)*128 + k, f32);
    xsT[k][r] = ldIn(x,  (size_t)sIdx[r]*128 + k, f32);
    xtT[k][r] = ldIn(x,  (size_t)tIdx[r]*128 + k, f32);
  }
  __syncthreads();

  const int j  = tid & 127;
  const int h8 = (tid >> 7) * 8;

  float aq[8], ak[8], aw[8], ab[8];
  #pragma unroll
  for (int i=0;i<8;i++){ aq[i]=0.f; ak[i]=0.f; aw[i]=0.f; ab[i]=0.f; }

  for (int k=0;k<128;k++){
    const float wq = ldIn(W_Q,  (size_t)k*128 + j, f32);
    const float wk = ldIn(W_K,  (size_t)k*128 + j, f32);
    const float ww = ldIn(W_Ew, (size_t)k*128 + j, f32);
    const float wb = ldIn(W_Eb, (size_t)k*128 + j, f32);
    const float4 s0 = *reinterpret_cast<const float4*>(&xsT[k][h8]);
    const float4 s1 = *reinterpret_cast<const float4*>(&xsT[k][h8+4]);
    const float4 t0 = *reinterpret_cast<const float4*>(&xtT[k][h8]);
    const float4 t1 = *reinterpret_cast<const float4*>(&xtT[k][h8+4]);
    const float4 e0v = *reinterpret_cast<const float4*>(&eaT[k][h8]);
    const float4 e1v = *reinterpret_cast<const float4*>(&eaT[k][h8+4]);
    const float sv[8] = {s0.x,s0.y,s0.z,s0.w,s1.x,s1.y,s1.z,s1.w};
    const float tv[8] = {t0.x,t0.y,t0.z,t0.w,t1.x,t1.y,t1.z,t1.w};
    const float ev[8] = {e0v.x,e0v.y,e0v.z,e0v.w,e1v.x,e1v.y,e1v.z,e1v.w};
    #pragma unroll
    for (int i=0;i<8;i++){
      aq[i] = fmaf(sv[i], wq, aq[i]);
      ak[i] = fmaf(tv[i], wk, ak[i]);
      aw[i] = fmaf(ev[i], ww, aw[i]);
      ab[i] = fmaf(ev[i], wb, ab[i]);
    }
  }

  const float bq = ldIn(b_Q, j, f32),  bk = ldIn(b_K, j, f32);
  const float bw = ldIn(b_Ew, j, f32), bb = ldIn(b_Eb, j, f32);
  #pragma unroll
  for (int i=0;i<8;i++){
    const int el = h8 + i;
    const float q  = aq[i] + bq;
    const float kk = ak[i] + bk;
    const float ew = aw[i] + bw;
    const float eb = ab[i] + bb;
    const float pre = (q + kk) * ew;
    const float ssv = pre > 0.f ?  sqrtf( pre + 1e-8f)
                    : (pre < 0.f ? -sqrtf(-pre + 1e-8f) : 0.f);
    afL[el][j] = fmaxf(ssv + eb, 0.f);
  }
  __syncthreads();

  if (tid < 128){
    const int el = tid >> 3, h = tid & 7;
    float sum = ldIn(b_A, h, f32);
    for (int jj=0; jj<128; jj++)
      sum = fmaf(afL[el][jj], ldIn(W_A, (size_t)jj*8 + h, f32), sum);
    sum = san(sum);
    scores[(size_t)(e0 + el)*8 + h] = sum;
    atomicMax(&segmax[(size_t)tIdx[el]*8 + h], fmap(sum));
  }
}

__global__ __launch_bounds__(256) void seg_sum_k(const float* __restrict__ scores,
    const int* __restrict__ eidx, const unsigned* __restrict__ segmax,
    float* __restrict__ segsum)
{
  int i = blockIdx.x*256 + threadIdx.x;
  if (i >= N_EDGES*8) return;
  int e = i >> 3, h = i & 7;
  int t = eidx[N_EDGES + e];
  float m = funmap(segmax[(size_t)t*8 + h]);
  atomicAdd(&segsum[(size_t)t*8 + h], expf(scores[i] - m));
}

// ---- messages: per 16-edge block, fused GEMVs V[src], Ev -> alpha-weighted
// scatter-add into agg (f32, lives in the out_e region of d_out).
__global__ __launch_bounds__(256) void messages_full(
    const void* __restrict__ x, const void* __restrict__ ea,
    const int* __restrict__ eidx,
    const void* __restrict__ W_V,  const void* __restrict__ b_V,
    const void* __restrict__ W_Ev, const void* __restrict__ b_Ev,
    const float* __restrict__ scores, const unsigned* __restrict__ segmax,
    const float* __restrict__ segsum, void* __restrict__ outp,
    const int* __restrict__ flagp)
{
  const int f32 = *flagp;
  float* agg = (float*)((char*)outp + (f32 ? AGG_OFF_F32 : AGG_OFF_BF16));
  __shared__ float eaT[128][16], xsT[128][16];
  __shared__ int sIdx[16], tIdx[16];

  const int tid = threadIdx.x;
  const int e0  = blockIdx.x * 16;

  if (tid < 16){
    sIdx[tid] = eidx[e0 + tid];
    tIdx[tid] = eidx[N_EDGES + e0 + tid];
  }
  __syncthreads();

  for (int idx = tid; idx < 16*128; idx += 256){
    int r = idx >> 7, k = idx & 127;
    eaT[k][r] = ldIn(ea, (size_t)(e0 + r)*128 + k, f32);
    xsT[k][r] = ldIn(x,  (size_t)sIdx[r]*128 + k, f32);
  }
  __syncthreads();

  const int j  = tid & 127;
  const int h8 = (tid >> 7) * 8;

  float av[8], ae[8];
  #pragma unroll
  for (int i=0;i<8;i++){ av[i]=0.f; ae[i]=0.f; }

  for (int k=0;k<128;k++){
    const float wv = ldIn(W_V,  (size_t)k*128 + j, f32);
    const float we = ldIn(W_Ev, (size_t)k*128 + j, f32);
    const float4 s0 = *reinterpret_cast<const float4*>(&xsT[k][h8]);
    const float4 s1 = *reinterpret_cast<const float4*>(&xsT[k][h8+4]);
    const float4 e0v = *reinterpret_cast<const float4*>(&eaT[k][h8]);
    const float4 e1v = *reinterpret_cast<const float4*>(&eaT[k][h8+4]);
    const float sv[8] = {s0.x,s0.y,s0.z,s0.w,s1.x,s1.y,s1.z,s1.w};
    const float ev[8] = {e0v.x,e0v.y,e0v.z,e0v.w,e1v.x,e1v.y,e1v.z,e1v.w};
    #pragma unroll
    for (int i=0;i<8;i++){
      av[i] = fmaf(sv[i], wv, av[i]);
      ae[i] = fmaf(ev[i], we, ae[i]);
    }
  }

  const float bv = ldIn(b_V, j, f32), be = ldIn(b_Ev, j, f32);
  const int h = j >> 4;
  #pragma unroll
  for (int i=0;i<8;i++){
    const int el = h8 + i;
    const size_t e = (size_t)e0 + el;
    const int t = tIdx[el];
    const float m   = funmap(segmax[(size_t)t*8 + h]);
    const float den = segsum[(size_t)t*8 + h] + 1e-16f;
    const float a   = expf(scores[e*8 + h] - m) / den;
    const float msg = san(((av[i] + bv) + (ae[i] + be)) * a);
    atomicAdd(&agg[(size_t)t*128 + j], msg);
  }
}

// ---- x_out = agg @ W_O + b_O  (agg f32 in out_e region; writes out_x region)
__global__ __launch_bounds__(256) void oproj(void* __restrict__ outp,
    const void* __restrict__ W, const void* __restrict__ bias,
    const int* __restrict__ flagp)
{
  const int f32 = *flagp;
  const float* agg = (const float*)((const char*)outp + (f32 ? AGG_OFF_F32 : AGG_OFF_BF16));
  __shared__ float AT[128][32];
  const int tid  = threadIdx.x;
  const int base = blockIdx.x * 32;

  for (int idx = tid; idx < 32*128; idx += 256){
    int r = idx >> 7, k = idx & 127;
    AT[k][r] = agg[(size_t)(base + r)*128 + k];
  }
  __syncthreads();

  const int j  = tid & 127;
  const int rb = (tid >> 7) * 16;
  float acc[16];
  #pragma unroll
  for (int i=0;i<16;i++) acc[i] = 0.f;

  for (int k=0;k<128;k++){
    const float w = ldIn(W, (size_t)k*128 + j, f32);
    const float4 a0 = *reinterpret_cast<const float4*>(&AT[k][rb]);
    const float4 a1 = *reinterpret_cast<const float4*>(&AT[k][rb+4]);
    const float4 a2 = *reinterpret_cast<const float4*>(&AT[k][rb+8]);
    const float4 a3 = *reinterpret_cast<const float4*>(&AT[k][rb+12]);
    const float avv[16] = {a0.x,a0.y,a0.z,a0.w,a1.x,a1.y,a1.z,a1.w,
                           a2.x,a2.y,a2.z,a2.w,a3.x,a3.y,a3.z,a3.w};
    #pragma unroll
    for (int i=0;i<16;i++) acc[i] = fmaf(avv[i], w, acc[i]);
  }

  const float bj = ldIn(bias, j, f32);
  #pragma unroll
  for (int i=0;i<16;i++)
    stOut(outp, (size_t)(base + rb + i)*128 + j, san(acc[i] + bj), f32);
}

// ---- edge output: recompute attn_feat (same front as edge_score), then
// af @ W_Eo + b_Eo -> out_e rows. Reads only inputs; writes only out_e.
__global__ __launch_bounds__(256) void eo_full(
    const void* __restrict__ x, const void* __restrict__ ea,
    const int* __restrict__ eidx,
    const void* __restrict__ W_Q, const void* __restrict__ b_Q,
    const void* __restrict__ W_K, const void* __restrict__ b_K,
    const void* __restrict__ W_Ew, const void* __restrict__ b_Ew,
    const void* __restrict__ W_Eb, const void* __restrict__ b_Eb,
    const void* __restrict__ W_Eo, const void* __restrict__ b_Eo,
    void* __restrict__ outp, const int* __restrict__ flagp)
{
  const int f32 = *flagp;
  __shared__ float eaT[128][16], xsT[128][16], xtT[128][16];
  __shared__ float afL[16][132];
  __shared__ int sIdx[16], tIdx[16];

  const int tid = threadIdx.x;
  const int e0  = blockIdx.x * 16;

  if (tid < 16){
    sIdx[tid] = eidx[e0 + tid];
    tIdx[tid] = eidx[N_EDGES + e0 + tid];
  }
  __syncthreads();

  for (int idx = tid; idx < 16*128; idx += 256){
    int r = idx >> 7, k = idx & 127;
    eaT[k][r] = ldIn(ea, (size_t)(e0 + r)*128 + k, f32);
    xsT[k][r] = ldIn(x,  (size_t)sIdx[r]*128 + k, f32);
    xtT[k][r] = ldIn(x,  (size_t)tIdx[r]*128 + k, f32);
  }
  __syncthreads();

  const int j  = tid & 127;
  const int h8 = (tid >> 7) * 8;

  {
    float aq[8], ak[8], aw[8], ab[8];
    #pragma unroll
    for (int i=0;i<8;i++){ aq[i]=0.f; ak[i]=0.f; aw[i]=0.f; ab[i]=0.f; }

    for (int k=0;k<128;k++){
      const float wq = ldIn(W_Q,  (size_t)k*128 + j, f32);
      const float wk = ldIn(W_K,  (size_t)k*128 + j, f32);
      const float ww = ldIn(W_Ew, (size_t)k*128 + j, f32);
      const float wb = ldIn(W_Eb, (size_t)k*128 + j, f32);
      const float4 s0 = *reinterpret_cast<const float4*>(&xsT[k][h8]);
      const float4 s1 = *reinterpret_cast<const float4*>(&xsT[k][h8+4]);
      const float4 t0 = *reinterpret_cast<const float4*>(&xtT[k][h8]);
      const float4 t1 = *reinterpret_cast<const float4*>(&xtT[k][h8+4]);
      const float4 e0v = *reinterpret_cast<const float4*>(&eaT[k][h8]);
      const float4 e1v = *reinterpret_cast<const float4*>(&eaT[k][h8+4]);
      const float sv[8] = {s0.x,s0.y,s0.z,s0.w,s1.x,s1.y,s1.z,s1.w};
      const float tv[8] = {t0.x,t0.y,t0.z,t0.w,t1.x,t1.y,t1.z,t1.w};
      const float evv[8] = {e0v.x,e0v.y,e0v.z,e0v.w,e1v.x,e1v.y,e1v.z,e1v.w};
      #pragma unroll
      for (int i=0;i<8;i++){
        aq[i] = fmaf(sv[i], wq, aq[i]);
        ak[i] = fmaf(tv[i], wk, ak[i]);
        aw[i] = fmaf(evv[i], ww, aw[i]);
        ab[i] = fmaf(evv[i], wb, ab[i]);
      }
    }

    const float bq = ldIn(b_Q, j, f32),  bk = ldIn(b_K, j, f32);
    const float bw = ldIn(b_Ew, j, f32), bb = ldIn(b_Eb, j, f32);
    #pragma unroll
    for (int i=0;i<8;i++){
      const int el = h8 + i;
      const float q  = aq[i] + bq;
      const float kk = ak[i] + bk;
      const float ew = aw[i] + bw;
      const float eb = ab[i] + bb;
      const float pre = (q + kk) * ew;
      const float ssv = pre > 0.f ?  sqrtf( pre + 1e-8f)
                      : (pre < 0.f ? -sqrtf(-pre + 1e-8f) : 0.f);
      afL[el][j] = fmaxf(ssv + eb, 0.f);
    }
  }
  __syncthreads();

  float acc[8];
  #pragma unroll
  for (int i=0;i<8;i++) acc[i] = 0.f;
  for (int jj=0; jj<128; jj++){
    const float w = ldIn(W_Eo, (size_t)jj*128 + j, f32);
    #pragma unroll
    for (int i=0;i<8;i++) acc[i] = fmaf(afL[h8+i][jj], w, acc[i]);
  }
  const float be = ldIn(b_Eo, j, f32);
  #pragma unroll
  for (int i=0;i<8;i++)
    stOut(outp, OUT_E_ELEM + (size_t)(e0 + h8 + i)*128 + j, san(acc[i] + be), f32);
}

extern "C" void kernel_launch(void* const* d_in, const int* in_sizes, int n_in,
                              void* d_out, int out_size, void* d_ws, size_t ws_size,
                              hipStream_t stream)
{
  (void)in_sizes; (void)n_in; (void)out_size; (void)ws_size;
  const void* x    = d_in[0];
  const void* ea   = d_in[1];
  const int*  eidx = (const int*)d_in[2];
  const void* W_Q  = d_in[4];  const void* b_Q  = d_in[5];
  const void* W_K  = d_in[6];  const void* b_K  = d_in[7];
  const void* W_V  = d_in[8];  const void* b_V  = d_in[9];
  const void* W_Ew = d_in[10]; const void* b_Ew = d_in[11];
  const void* W_Eb = d_in[12]; const void* b_Eb = d_in[13];
  const void* W_Ev = d_in[14]; const void* b_Ev = d_in[15];
  const void* W_O  = d_in[16]; const void* b_O  = d_in[17];
  const void* W_Eo = d_in[18]; const void* b_Eo = d_in[19];
  const void* W_A  = d_in[20]; const void* b_A  = d_in[21];

  int* flag = (int*)d_ws;                              // 4 bytes of ws, total

  // scores/segmax/segsum live in the out_x region (dead before oproj writes it)
  float*    scores = (float*)d_out;
  unsigned* segmax = (unsigned*)((char*)d_out + SCORES_B);
  float*    segsum = (float*)((char*)d_out + SCORES_B + SEG_B);

  dim3 blk(256);

  detect_dtype<<<dim3(1), dim3(64), 0, stream>>>(W_Q, flag);

  // zero segmax+segsum (6.4 MB) and the agg union region [25.6MB, 102.4MB)
  hipMemsetAsync((char*)d_out + SCORES_B, 0, 2*SEG_B, stream);
  hipMemsetAsync((char*)d_out + AGG_OFF_BF16, 0,
                 (AGG_OFF_F32 - AGG_OFF_BF16) + AGG_BYTES, stream);

  edge_score<<<dim3(N_EDGES/16), blk, 0, stream>>>(x, ea, eidx,
      W_Q, b_Q, W_K, b_K, W_Ew, b_Ew, W_Eb, b_Eb, W_A, b_A,
      scores, segmax, flag);

  seg_sum_k<<<dim3((N_EDGES*8 + 255)/256), blk, 0, stream>>>(scores, eidx, segmax, segsum);

  messages_full<<<dim3(N_EDGES/16), blk, 0, stream>>>(x, ea, eidx,
      W_V, b_V, W_Ev, b_Ev, scores, segmax, segsum, d_out, flag);

  // x_out (overwrites scores/segmax/segsum region — all dead by now)
  oproj<<<dim3(N_NODES/32), blk, 0, stream>>>(d_out, W_O, b_O, flag);

  // edge_attr_out (overwrites out_e region incl. agg — dead after oproj)
  eo_full<<<dim3(N_EDGES/16), blk, 0, stream>>>(x, ea, eidx,
      W_Q, b_Q, W_K, b_K, W_Ew, b_Ew, W_Eb, b_Eb, W_Eo, b_Eo, d_out, flag);
}

// Round 10
// 3276.921 us; speedup vs baseline: 1.1941x; 1.1941x over previous
//
#include <hip/hip_runtime.h>
#include <hip/hip_bf16.h>

typedef __hip_bfloat16 bf16;

#define N_NODES 100000
#define N_EDGES 400000
#define HALF_E  200000

// ---- byte/element offsets inside d_out ----
#define OUT_E_ELEM   ((size_t)N_NODES*128)            // element offset of out_e
#define SCORES_B     ((size_t)N_EDGES*8*4)            // 12.8 MB
#define SEG_B        ((size_t)N_NODES*8*4)            //  3.2 MB
#define AGG_OFF_BF16 ((size_t)N_NODES*128*2)          // 25.6 MB (start of out_e, bf16)
#define AGG_OFF_F32  ((size_t)N_NODES*128*4)          // 51.2 MB (start of out_e, f32)
#define AGG_BYTES    ((size_t)N_NODES*128*4)          // 51.2 MB

__device__ __forceinline__ float b2f(bf16 v){ return __bfloat162float(v); }
__device__ __forceinline__ bf16  f2b(float v){ return __float2bfloat16(v); }

__device__ __forceinline__ float ldIn(const void* p, size_t i, int f32){
  return f32 ? ((const float*)p)[i] : b2f(((const bf16*)p)[i]);
}
__device__ __forceinline__ void stOut(void* p, size_t i, float v, int f32){
  if (f32) ((float*)p)[i] = v; else ((bf16*)p)[i] = f2b(v);
}
__device__ __forceinline__ float san(float v){
  return (v == v && fabsf(v) < 1e30f) ? v : 0.f;
}

__device__ __forceinline__ unsigned fmap(float f){
  unsigned u = __float_as_uint(f);
  return (u & 0x80000000u) ? ~u : (u | 0x80000000u);
}
__device__ __forceinline__ float funmap(unsigned u){
  unsigned b = (u & 0x80000000u) ? (u ^ 0x80000000u) : ~u;
  return __uint_as_float(b);
}

// ---- dtype detector (proven)
__global__ void detect_dtype_v10(const void* w, int* flag){
  __shared__ int cnt;
  if (threadIdx.x == 0) cnt = 0;
  __syncthreads();
  const bf16* p = (const bf16*)w;
  int c = 0;
  for (int i = threadIdx.x; i < 256; i += 64){
    float v = b2f(p[i]);
    if (!(v == v) || fabsf(v) > 1.0f) c++;
  }
  atomicAdd(&cnt, c);
  __syncthreads();
  if (threadIdx.x == 0) *flag = (cnt > 32) ? 1 : 0;
}

// ---- edge front-end (proven body + fused Eo tail for e0 >= HALF_E)
__global__ __launch_bounds__(256) void edge_score_v10(
    const void* __restrict__ x, const void* __restrict__ ea,
    const int* __restrict__ eidx,
    const void* __restrict__ W_Q, const void* __restrict__ b_Q,
    const void* __restrict__ W_K, const void* __restrict__ b_K,
    const void* __restrict__ W_Ew, const void* __restrict__ b_Ew,
    const void* __restrict__ W_Eb, const void* __restrict__ b_Eb,
    const void* __restrict__ W_A,  const void* __restrict__ b_A,
    const void* __restrict__ W_Eo, const void* __restrict__ b_Eo,
    float* __restrict__ scores, unsigned* __restrict__ segmax,
    void* __restrict__ outp,
    const int* __restrict__ flagp)
{
  const int f32 = *flagp;
  __shared__ float eaT[128][16], xsT[128][16], xtT[128][16];
  __shared__ float afL[16][132];
  __shared__ int sIdx[16], tIdx[16];

  const int tid = threadIdx.x;
  const int e0  = blockIdx.x * 16;

  if (tid < 16){
    sIdx[tid] = eidx[e0 + tid];
    tIdx[tid] = eidx[N_EDGES + e0 + tid];
  }
  __syncthreads();

  for (int idx = tid; idx < 16*128; idx += 256){
    int r = idx >> 7, k = idx & 127;
    eaT[k][r] = ldIn(ea, (size_t)(e0 + r)*128 + k, f32);
    xsT[k][r] = ldIn(x,  (size_t)sIdx[r]*128 + k, f32);
    xtT[k][r] = ldIn(x,  (size_t)tIdx[r]*128 + k, f32);
  }
  __syncthreads();

  const int j  = tid & 127;
  const int h8 = (tid >> 7) * 8;

  float aq[8], ak[8], aw[8], ab[8];
  #pragma unroll
  for (int i=0;i<8;i++){ aq[i]=0.f; ak[i]=0.f; aw[i]=0.f; ab[i]=0.f; }

  for (int k=0;k<128;k++){
    const float wq = ldIn(W_Q,  (size_t)k*128 + j, f32);
    const float wk = ldIn(W_K,  (size_t)k*128 + j, f32);
    const float ww = ldIn(W_Ew, (size_t)k*128 + j, f32);
    const float wb = ldIn(W_Eb, (size_t)k*128 + j, f32);
    const float4 s0 = *reinterpret_cast<const float4*>(&xsT[k][h8]);
    const float4 s1 = *reinterpret_cast<const float4*>(&xsT[k][h8+4]);
    const float4 t0 = *reinterpret_cast<const float4*>(&xtT[k][h8]);
    const float4 t1 = *reinterpret_cast<const float4*>(&xtT[k][h8+4]);
    const float4 e0v = *reinterpret_cast<const float4*>(&eaT[k][h8]);
    const float4 e1v = *reinterpret_cast<const float4*>(&eaT[k][h8+4]);
    const float sv[8] = {s0.x,s0.y,s0.z,s0.w,s1.x,s1.y,s1.z,s1.w};
    const float tv[8] = {t0.x,t0.y,t0.z,t0.w,t1.x,t1.y,t1.z,t1.w};
    const float ev[8] = {e0v.x,e0v.y,e0v.z,e0v.w,e1v.x,e1v.y,e1v.z,e1v.w};
    #pragma unroll
    for (int i=0;i<8;i++){
      aq[i] = fmaf(sv[i], wq, aq[i]);
      ak[i] = fmaf(tv[i], wk, ak[i]);
      aw[i] = fmaf(ev[i], ww, aw[i]);
      ab[i] = fmaf(ev[i], wb, ab[i]);
    }
  }

  const float bq = ldIn(b_Q, j, f32),  bk = ldIn(b_K, j, f32);
  const float bw = ldIn(b_Ew, j, f32), bb = ldIn(b_Eb, j, f32);
  #pragma unroll
  for (int i=0;i<8;i++){
    const int el = h8 + i;
    const float q  = aq[i] + bq;
    const float kk = ak[i] + bk;
    const float ew = aw[i] + bw;
    const float eb = ab[i] + bb;
    const float pre = (q + kk) * ew;
    const float ssv = pre > 0.f ?  sqrtf( pre + 1e-8f)
                    : (pre < 0.f ? -sqrtf(-pre + 1e-8f) : 0.f);
    afL[el][j] = fmaxf(ssv + eb, 0.f);
  }
  __syncthreads();

  if (tid < 128){
    const int el = tid >> 3, h = tid & 7;
    float sum = ldIn(b_A, h, f32);
    for (int jj=0; jj<128; jj++)
      sum = fmaf(afL[el][jj], ldIn(W_A, (size_t)jj*8 + h, f32), sum);
    sum = san(sum);
    scores[(size_t)(e0 + el)*8 + h] = sum;
    atomicMax(&segmax[(size_t)tIdx[el]*8 + h], fmap(sum));
  }

  // ---- fused Eo tail (same math as eo_full's tail) for the upper-half edges,
  // whose out_e rows [HALF_E,N_EDGES) don't overlap agg. Block-uniform predicate.
  if (e0 >= HALF_E){
    float acc[8];
    #pragma unroll
    for (int i=0;i<8;i++) acc[i] = 0.f;
    for (int jj=0; jj<128; jj++){
      const float w = ldIn(W_Eo, (size_t)jj*128 + j, f32);
      #pragma unroll
      for (int i=0;i<8;i++) acc[i] = fmaf(afL[h8+i][jj], w, acc[i]);
    }
    const float be = ldIn(b_Eo, j, f32);
    #pragma unroll
    for (int i=0;i<8;i++)
      stOut(outp, OUT_E_ELEM + (size_t)(e0 + h8 + i)*128 + j, san(acc[i] + be), f32);
  }
}

__global__ __launch_bounds__(256) void seg_sum_v10(const float* __restrict__ scores,
    const int* __restrict__ eidx, const unsigned* __restrict__ segmax,
    float* __restrict__ segsum)
{
  int i = blockIdx.x*256 + threadIdx.x;
  if (i >= N_EDGES*8) return;
  int e = i >> 3, h = i & 7;
  int t = eidx[N_EDGES + e];
  float m = funmap(segmax[(size_t)t*8 + h]);
  atomicAdd(&segsum[(size_t)t*8 + h], expf(scores[i] - m));
}

// ---- messages (proven body)
__global__ __launch_bounds__(256) void messages_v10(
    const void* __restrict__ x, const void* __restrict__ ea,
    const int* __restrict__ eidx,
    const void* __restrict__ W_V,  const void* __restrict__ b_V,
    const void* __restrict__ W_Ev, const void* __restrict__ b_Ev,
    const float* __restrict__ scores, const unsigned* __restrict__ segmax,
    const float* __restrict__ segsum, void* __restrict__ outp,
    const int* __restrict__ flagp)
{
  const int f32 = *flagp;
  float* agg = (float*)((char*)outp + (f32 ? AGG_OFF_F32 : AGG_OFF_BF16));
  __shared__ float eaT[128][16], xsT[128][16];
  __shared__ int sIdx[16], tIdx[16];

  const int tid = threadIdx.x;
  const int e0  = blockIdx.x * 16;

  if (tid < 16){
    sIdx[tid] = eidx[e0 + tid];
    tIdx[tid] = eidx[N_EDGES + e0 + tid];
  }
  __syncthreads();

  for (int idx = tid; idx < 16*128; idx += 256){
    int r = idx >> 7, k = idx & 127;
    eaT[k][r] = ldIn(ea, (size_t)(e0 + r)*128 + k, f32);
    xsT[k][r] = ldIn(x,  (size_t)sIdx[r]*128 + k, f32);
  }
  __syncthreads();

  const int j  = tid & 127;
  const int h8 = (tid >> 7) * 8;

  float av[8], ae[8];
  #pragma unroll
  for (int i=0;i<8;i++){ av[i]=0.f; ae[i]=0.f; }

  for (int k=0;k<128;k++){
    const float wv = ldIn(W_V,  (size_t)k*128 + j, f32);
    const float we = ldIn(W_Ev, (size_t)k*128 + j, f32);
    const float4 s0 = *reinterpret_cast<const float4*>(&xsT[k][h8]);
    const float4 s1 = *reinterpret_cast<const float4*>(&xsT[k][h8+4]);
    const float4 e0v = *reinterpret_cast<const float4*>(&eaT[k][h8]);
    const float4 e1v = *reinterpret_cast<const float4*>(&eaT[k][h8+4]);
    const float sv[8] = {s0.x,s0.y,s0.z,s0.w,s1.x,s1.y,s1.z,s1.w};
    const float ev[8] = {e0v.x,e0v.y,e0v.z,e0v.w,e1v.x,e1v.y,e1v.z,e1v.w};
    #pragma unroll
    for (int i=0;i<8;i++){
      av[i] = fmaf(sv[i], wv, av[i]);
      ae[i] = fmaf(ev[i], we, ae[i]);
    }
  }

  const float bv = ldIn(b_V, j, f32), be = ldIn(b_Ev, j, f32);
  const int h = j >> 4;
  #pragma unroll
  for (int i=0;i<8;i++){
    const int el = h8 + i;
    const size_t e = (size_t)e0 + el;
    const int t = tIdx[el];
    const float m   = funmap(segmax[(size_t)t*8 + h]);
    const float den = segsum[(size_t)t*8 + h] + 1e-16f;
    const float a   = expf(scores[e*8 + h] - m) / den;
    const float msg = san(((av[i] + bv) + (ae[i] + be)) * a);
    atomicAdd(&agg[(size_t)t*128 + j], msg);
  }
}

// ---- x_out = agg @ W_O + b_O (proven body)
__global__ __launch_bounds__(256) void oproj_v10(void* __restrict__ outp,
    const void* __restrict__ W, const void* __restrict__ bias,
    const int* __restrict__ flagp)
{
  const int f32 = *flagp;
  const float* agg = (const float*)((const char*)outp + (f32 ? AGG_OFF_F32 : AGG_OFF_BF16));
  __shared__ float AT[128][32];
  const int tid  = threadIdx.x;
  const int base = blockIdx.x * 32;

  for (int idx = tid; idx < 32*128; idx += 256){
    int r = idx >> 7, k = idx & 127;
    AT[k][r] = agg[(size_t)(base + r)*128 + k];
  }
  __syncthreads();

  const int j  = tid & 127;
  const int rb = (tid >> 7) * 16;
  float acc[16];
  #pragma unroll
  for (int i=0;i<16;i++) acc[i] = 0.f;

  for (int k=0;k<128;k++){
    const float w = ldIn(W, (size_t)k*128 + j, f32);
    const float4 a0 = *reinterpret_cast<const float4*>(&AT[k][rb]);
    const float4 a1 = *reinterpret_cast<const float4*>(&AT[k][rb+4]);
    const float4 a2 = *reinterpret_cast<const float4*>(&AT[k][rb+8]);
    const float4 a3 = *reinterpret_cast<const float4*>(&AT[k][rb+12]);
    const float avv[16] = {a0.x,a0.y,a0.z,a0.w,a1.x,a1.y,a1.z,a1.w,
                           a2.x,a2.y,a2.z,a2.w,a3.x,a3.y,a3.z,a3.w};
    #pragma unroll
    for (int i=0;i<16;i++) acc[i] = fmaf(avv[i], w, acc[i]);
  }

  const float bj = ldIn(bias, j, f32);
  #pragma unroll
  for (int i=0;i<16;i++)
    stOut(outp, (size_t)(base + rb + i)*128 + j, san(acc[i] + bj), f32);
}

// ---- recompute front + Eo GEMM (proven body; now only the LOWER half grid)
__global__ __launch_bounds__(256) void eo_full_v10(
    const void* __restrict__ x, const void* __restrict__ ea,
    const int* __restrict__ eidx,
    const void* __restrict__ W_Q, const void* __restrict__ b_Q,
    const void* __restrict__ W_K, const void* __restrict__ b_K,
    const void* __restrict__ W_Ew, const void* __restrict__ b_Ew,
    const void* __restrict__ W_Eb, const void* __restrict__ b_Eb,
    const void* __restrict__ W_Eo, const void* __restrict__ b_Eo,
    void* __restrict__ outp, const int* __restrict__ flagp)
{
  const int f32 = *flagp;
  __shared__ float eaT[128][16], xsT[128][16], xtT[128][16];
  __shared__ float afL[16][132];
  __shared__ int sIdx[16], tIdx[16];

  const int tid = threadIdx.x;
  const int e0  = blockIdx.x * 16;

  if (tid < 16){
    sIdx[tid] = eidx[e0 + tid];
    tIdx[tid] = eidx[N_EDGES + e0 + tid];
  }
  __syncthreads();

  for (int idx = tid; idx < 16*128; idx += 256){
    int r = idx >> 7, k = idx & 127;
    eaT[k][r] = ldIn(ea, (size_t)(e0 + r)*128 + k, f32);
    xsT[k][r] = ldIn(x,  (size_t)sIdx[r]*128 + k, f32);
    xtT[k][r] = ldIn(x,  (size_t)tIdx[r]*128 + k, f32);
  }
  __syncthreads();

  const int j  = tid & 127;
  const int h8 = (tid >> 7) * 8;

  {
    float aq[8], ak[8], aw[8], ab[8];
    #pragma unroll
    for (int i=0;i<8;i++){ aq[i]=0.f; ak[i]=0.f; aw[i]=0.f; ab[i]=0.f; }

    for (int k=0;k<128;k++){
      const float wq = ldIn(W_Q,  (size_t)k*128 + j, f32);
      const float wk = ldIn(W_K,  (size_t)k*128 + j, f32);
      const float ww = ldIn(W_Ew, (size_t)k*128 + j, f32);
      const float wb = ldIn(W_Eb, (size_t)k*128 + j, f32);
      const float4 s0 = *reinterpret_cast<const float4*>(&xsT[k][h8]);
      const float4 s1 = *reinterpret_cast<const float4*>(&xsT[k][h8+4]);
      const float4 t0 = *reinterpret_cast<const float4*>(&xtT[k][h8]);
      const float4 t1 = *reinterpret_cast<const float4*>(&xtT[k][h8+4]);
      const float4 e0v = *reinterpret_cast<const float4*>(&eaT[k][h8]);
      const float4 e1v = *reinterpret_cast<const float4*>(&eaT[k][h8+4]);
      const float sv[8] = {s0.x,s0.y,s0.z,s0.w,s1.x,s1.y,s1.z,s1.w};
      const float tv[8] = {t0.x,t0.y,t0.z,t0.w,t1.x,t1.y,t1.z,t1.w};
      const float evv[8] = {e0v.x,e0v.y,e0v.z,e0v.w,e1v.x,e1v.y,e1v.z,e1v.w};
      #pragma unroll
      for (int i=0;i<8;i++){
        aq[i] = fmaf(sv[i], wq, aq[i]);
        ak[i] = fmaf(tv[i], wk, ak[i]);
        aw[i] = fmaf(evv[i], ww, aw[i]);
        ab[i] = fmaf(evv[i], wb, ab[i]);
      }
    }

    const float bq = ldIn(b_Q, j, f32),  bk = ldIn(b_K, j, f32);
    const float bw = ldIn(b_Ew, j, f32), bb = ldIn(b_Eb, j, f32);
    #pragma unroll
    for (int i=0;i<8;i++){
      const int el = h8 + i;
      const float q  = aq[i] + bq;
      const float kk = ak[i] + bk;
      const float ew = aw[i] + bw;
      const float eb = ab[i] + bb;
      const float pre = (q + kk) * ew;
      const float ssv = pre > 0.f ?  sqrtf( pre + 1e-8f)
                      : (pre < 0.f ? -sqrtf(-pre + 1e-8f) : 0.f);
      afL[el][j] = fmaxf(ssv + eb, 0.f);
    }
  }
  __syncthreads();

  float acc[8];
  #pragma unroll
  for (int i=0;i<8;i++) acc[i] = 0.f;
  for (int jj=0; jj<128; jj++){
    const float w = ldIn(W_Eo, (size_t)jj*128 + j, f32);
    #pragma unroll
    for (int i=0;i<8;i++) acc[i] = fmaf(afL[h8+i][jj], w, acc[i]);
  }
  const float be = ldIn(b_Eo, j, f32);
  #pragma unroll
  for (int i=0;i<8;i++)
    stOut(outp, OUT_E_ELEM + (size_t)(e0 + h8 + i)*128 + j, san(acc[i] + be), f32);
}

extern "C" void kernel_launch(void* const* d_in, const int* in_sizes, int n_in,
                              void* d_out, int out_size, void* d_ws, size_t ws_size,
                              hipStream_t stream)
{
  (void)in_sizes; (void)n_in; (void)out_size; (void)ws_size;
  const void* x    = d_in[0];
  const void* ea   = d_in[1];
  const int*  eidx = (const int*)d_in[2];
  const void* W_Q  = d_in[4];  const void* b_Q  = d_in[5];
  const void* W_K  = d_in[6];  const void* b_K  = d_in[7];
  const void* W_V  = d_in[8];  const void* b_V  = d_in[9];
  const void* W_Ew = d_in[10]; const void* b_Ew = d_in[11];
  const void* W_Eb = d_in[12]; const void* b_Eb = d_in[13];
  const void* W_Ev = d_in[14]; const void* b_Ev = d_in[15];
  const void* W_O  = d_in[16]; const void* b_O  = d_in[17];
  const void* W_Eo = d_in[18]; const void* b_Eo = d_in[19];
  const void* W_A  = d_in[20]; const void* b_A  = d_in[21];

  int* flag = (int*)d_ws;                              // 4 bytes of ws, total

  // scores/segmax/segsum live in the out_x region (dead before oproj writes it)
  float*    scores = (float*)d_out;
  unsigned* segmax = (unsigned*)((char*)d_out + SCORES_B);
  float*    segsum = (float*)((char*)d_out + SCORES_B + SEG_B);

  dim3 blk(256);

  detect_dtype_v10<<<dim3(1), dim3(64), 0, stream>>>(W_Q, flag);

  // zero segmax+segsum (6.4 MB) and the agg union region [25.6MB, 102.4MB)
  hipMemsetAsync((char*)d_out + SCORES_B, 0, 2*SEG_B, stream);
  hipMemsetAsync((char*)d_out + AGG_OFF_BF16, 0,
                 (AGG_OFF_F32 - AGG_OFF_BF16) + AGG_BYTES, stream);

  // scores+segmax for all edges; fused Eo output for edges [HALF_E, N_EDGES)
  edge_score_v10<<<dim3(N_EDGES/16), blk, 0, stream>>>(x, ea, eidx,
      W_Q, b_Q, W_K, b_K, W_Ew, b_Ew, W_Eb, b_Eb, W_A, b_A, W_Eo, b_Eo,
      scores, segmax, d_out, flag);

  seg_sum_v10<<<dim3((N_EDGES*8 + 255)/256), blk, 0, stream>>>(scores, eidx, segmax, segsum);

  messages_v10<<<dim3(N_EDGES/16), blk, 0, stream>>>(x, ea, eidx,
      W_V, b_V, W_Ev, b_Ev, scores, segmax, segsum, d_out, flag);

  // x_out (overwrites scores/segmax/segsum region — all dead by now)
  oproj_v10<<<dim3(N_NODES/32), blk, 0, stream>>>(d_out, W_O, b_O, flag);

  // edge_attr_out lower half only (overwrites agg region — dead after oproj)
  eo_full_v10<<<dim3(HALF_E/16), blk, 0, stream>>>(x, ea, eidx,
      W_Q, b_Q, W_K, b_K, W_Ew, b_Ew, W_Eb, b_Eb, W_Eo, b_Eo, d_out, flag);
}

// Round 12
// 1992.628 us; speedup vs baseline: 1.9637x; 1.6445x over previous
//
#include <hip/hip_runtime.h>
#include <hip/hip_bf16.h>

typedef __hip_bfloat16 bf16;

#define N_NODES 100000
#define N_EDGES 400000
#define HALF_E  200000

// ---- f32 geometry of d_out (proven via rounds 9/10 flag=1 execution) ----
#define OUT_E_ELEM   ((size_t)N_NODES*128)            // f32-element offset of out_e
#define SCORES_B     ((size_t)N_EDGES*8*4)            // 12.8 MB
#define SEG_B        ((size_t)N_NODES*8*4)            //  3.2 MB
#define AGG_BYTES    ((size_t)N_NODES*128*4)          // 51.2 MB

using short8 = __attribute__((ext_vector_type(8))) short;
using f32x4  = __attribute__((ext_vector_type(4))) float;

__device__ __forceinline__ float b2f(bf16 v){ return __bfloat162float(v); }
__device__ __forceinline__ bf16  f2b(float v){ return __float2bfloat16(v); }
__device__ __forceinline__ short bits(bf16 v){ short s; __builtin_memcpy(&s, &v, 2); return s; }
// split f32 into hi/lo bf16 bit patterns: v ~= hi + lo
__device__ __forceinline__ void split(float v, short& h, short& l){
  bf16 hb = f2b(v);
  h = bits(hb);
  l = bits(f2b(v - b2f(hb)));
}
__device__ __forceinline__ float san(float v){
  return (v == v && fabsf(v) < 1e30f) ? v : 0.f;
}
__device__ __forceinline__ unsigned fmap(float f){
  unsigned u = __float_as_uint(f);
  return (u & 0x80000000u) ? ~u : (u | 0x80000000u);
}
__device__ __forceinline__ float funmap(unsigned u){
  unsigned b = (u & 0x80000000u) ? (u ^ 0x80000000u) : ~u;
  return __uint_as_float(b);
}

// ---- MFMA edge front (f32 in/out, hi/lo-split bf16 MFMA):
// per 16-edge block, 4 waves compute Q=xs@W_Q, K=xt@W_K, Ew=ea@W_Ew, Eb=ea@W_Eb.
// Epilogue (proven math): af = relu(signed_sqrt((Q+K)*Ew)+Eb);
// DO_SCORE: scores = af@W_A (VALU) + segmax atomic.
// Blocks with e0 >= eo_min also emit Eo = af@W_Eo (split MFMA) into oute (f32).
template<bool DO_SCORE>
__global__ __launch_bounds__(256) void front_mfma_v12(
    const float* __restrict__ x, const float* __restrict__ ea,
    const int* __restrict__ eidx,
    const float* __restrict__ W_Q, const float* __restrict__ b_Q,
    const float* __restrict__ W_K, const float* __restrict__ b_K,
    const float* __restrict__ W_Ew, const float* __restrict__ b_Ew,
    const float* __restrict__ W_Eb, const float* __restrict__ b_Eb,
    const float* __restrict__ W_A,  const float* __restrict__ b_A,
    const float* __restrict__ W_Eo, const float* __restrict__ b_Eo,
    float* __restrict__ scores, unsigned* __restrict__ segmax,
    float* __restrict__ oute, int eo_min)
{
  __shared__ __align__(16) short AH[3][16][136];   // hi bf16 bits: 0=xs 1=xt 2=ea
  __shared__ __align__(16) short AL[3][16][136];   // lo bf16 bits
  __shared__ float mat[4][16][132];                // Q,K,Ew,Eb; mat[0] becomes af
  __shared__ int sIdx[16], tIdx[16];

  const int tid = threadIdx.x;
  const int e0  = blockIdx.x * 16;

  if (tid < 16){
    sIdx[tid] = eidx[e0 + tid];
    tIdx[tid] = eidx[N_EDGES + e0 + tid];
  }
  __syncthreads();

  for (int idx = tid; idx < 16*128; idx += 256){
    const int r = idx >> 7, k = idx & 127;
    short h, l;
    split(x[(size_t)sIdx[r]*128 + k], h, l);  AH[0][r][k] = h; AL[0][r][k] = l;
    split(x[(size_t)tIdx[r]*128 + k], h, l);  AH[1][r][k] = h; AL[1][r][k] = l;
    split(ea[(size_t)(e0 + r)*128 + k], h, l); AH[2][r][k] = h; AL[2][r][k] = l;
  }
  __syncthreads();

  const int wv = tid >> 6;
  const int mi = (tid & 63) & 15;    // A-row (edge) / B-col (n) / D-col
  const int kg = (tid & 63) >> 4;    // k-group 0..3

  {
    const int tsel = (wv <= 1) ? wv : 2;
    const float* Wp = (wv == 0) ? W_Q : (wv == 1) ? W_K : (wv == 2) ? W_Ew : W_Eb;

    for (int nt = 0; nt < 8; ++nt){
      f32x4 acc = {0.f, 0.f, 0.f, 0.f};
      #pragma unroll
      for (int ks = 0; ks < 4; ++ks){
        const int kb = ks*32 + kg*8;
        const short8 ah = *reinterpret_cast<const short8*>(&AH[tsel][mi][kb]);
        const short8 al = *reinterpret_cast<const short8*>(&AL[tsel][mi][kb]);
        short8 bh, bl;
        #pragma unroll
        for (int q = 0; q < 8; ++q){
          short h, l;
          split(Wp[(size_t)(kb + q)*128 + nt*16 + mi], h, l);
          bh[q] = h; bl[q] = l;
        }
        acc = __builtin_amdgcn_mfma_f32_16x16x32_bf16(ah, bh, acc, 0, 0, 0);
        acc = __builtin_amdgcn_mfma_f32_16x16x32_bf16(al, bh, acc, 0, 0, 0);
        acc = __builtin_amdgcn_mfma_f32_16x16x32_bf16(ah, bl, acc, 0, 0, 0);
      }
      #pragma unroll
      for (int q = 0; q < 4; ++q)
        mat[wv][kg*4 + q][nt*16 + mi] = acc[q];
    }
  }
  __syncthreads();

  // ---- elementwise af (proven math); mat[0] overwritten in place (unique owner)
  {
    const int j  = tid & 127;
    const int h8 = (tid >> 7) * 8;
    const float bq = b_Q[j],  bk = b_K[j];
    const float bw = b_Ew[j], bb = b_Eb[j];
    #pragma unroll
    for (int i = 0; i < 8; ++i){
      const int el = h8 + i;
      const float q  = mat[0][el][j] + bq;
      const float kk = mat[1][el][j] + bk;
      const float ew = mat[2][el][j] + bw;
      const float eb = mat[3][el][j] + bb;
      const float pre = (q + kk) * ew;
      const float ssv = pre > 0.f ?  sqrtf( pre + 1e-8f)
                      : (pre < 0.f ? -sqrtf(-pre + 1e-8f) : 0.f);
      mat[0][el][j] = fmaxf(ssv + eb, 0.f);
    }
  }
  __syncthreads();

  // ---- scores + segmax (proven body; af in mat[0])
  if (DO_SCORE && tid < 128){
    const int el = tid >> 3, h = tid & 7;
    float sum = b_A[h];
    for (int jj = 0; jj < 128; ++jj)
      sum = fmaf(mat[0][el][jj], W_A[jj*8 + h], sum);
    sum = san(sum);
    scores[(size_t)(e0 + el)*8 + h] = sum;
    atomicMax(&segmax[(size_t)tIdx[el]*8 + h], fmap(sum));
  }

  // ---- fused Eo = af @ W_Eo (split MFMA); block-uniform predicate; f32 stores
  if (e0 >= eo_min){
    #pragma unroll
    for (int t2 = 0; t2 < 2; ++t2){
      const int nt = wv*2 + t2;
      f32x4 acc = {0.f, 0.f, 0.f, 0.f};
      #pragma unroll
      for (int ks = 0; ks < 4; ++ks){
        const int kb = ks*32 + kg*8;
        short8 ah, al, bh, bl;
        #pragma unroll
        for (int q = 0; q < 8; ++q){
          short h, l;
          split(mat[0][mi][kb + q], h, l);
          ah[q] = h; al[q] = l;
          split(W_Eo[(size_t)(kb + q)*128 + nt*16 + mi], h, l);
          bh[q] = h; bl[q] = l;
        }
        acc = __builtin_amdgcn_mfma_f32_16x16x32_bf16(ah, bh, acc, 0, 0, 0);
        acc = __builtin_amdgcn_mfma_f32_16x16x32_bf16(al, bh, acc, 0, 0, 0);
        acc = __builtin_amdgcn_mfma_f32_16x16x32_bf16(ah, bl, acc, 0, 0, 0);
      }
      const float be = b_Eo[nt*16 + mi];
      #pragma unroll
      for (int q = 0; q < 4; ++q){
        const int er = kg*4 + q;
        oute[(size_t)(e0 + er)*128 + nt*16 + mi] = san(acc[q] + be);
      }
    }
  }
}

__global__ __launch_bounds__(256) void seg_sum_v12(const float* __restrict__ scores,
    const int* __restrict__ eidx, const unsigned* __restrict__ segmax,
    float* __restrict__ segsum)
{
  int i = blockIdx.x*256 + threadIdx.x;
  if (i >= N_EDGES*8) return;
  int e = i >> 3, h = i & 7;
  int t = eidx[N_EDGES + e];
  float m = funmap(segmax[(size_t)t*8 + h]);
  atomicAdd(&segsum[(size_t)t*8 + h], expf(scores[i] - m));
}

// ---- messages (r10-proven body, f32-native)
__global__ __launch_bounds__(256) void messages_v12(
    const float* __restrict__ x, const float* __restrict__ ea,
    const int* __restrict__ eidx,
    const float* __restrict__ W_V,  const float* __restrict__ b_V,
    const float* __restrict__ W_Ev, const float* __restrict__ b_Ev,
    const float* __restrict__ scores, const unsigned* __restrict__ segmax,
    const float* __restrict__ segsum, float* __restrict__ agg)
{
  __shared__ float eaT[128][16], xsT[128][16];
  __shared__ int sIdx[16], tIdx[16];

  const int tid = threadIdx.x;
  const int e0  = blockIdx.x * 16;

  if (tid < 16){
    sIdx[tid] = eidx[e0 + tid];
    tIdx[tid] = eidx[N_EDGES + e0 + tid];
  }
  __syncthreads();

  for (int idx = tid; idx < 16*128; idx += 256){
    int r = idx >> 7, k = idx & 127;
    eaT[k][r] = ea[(size_t)(e0 + r)*128 + k];
    xsT[k][r] = x[(size_t)sIdx[r]*128 + k];
  }
  __syncthreads();

  const int j  = tid & 127;
  const int h8 = (tid >> 7) * 8;

  float av[8], ae[8];
  #pragma unroll
  for (int i=0;i<8;i++){ av[i]=0.f; ae[i]=0.f; }

  for (int k=0;k<128;k++){
    const float wv = W_V[(size_t)k*128 + j];
    const float we = W_Ev[(size_t)k*128 + j];
    const float4 s0 = *reinterpret_cast<const float4*>(&xsT[k][h8]);
    const float4 s1 = *reinterpret_cast<const float4*>(&xsT[k][h8+4]);
    const float4 e0v = *reinterpret_cast<const float4*>(&eaT[k][h8]);
    const float4 e1v = *reinterpret_cast<const float4*>(&eaT[k][h8+4]);
    const float sv[8] = {s0.x,s0.y,s0.z,s0.w,s1.x,s1.y,s1.z,s1.w};
    const float ev[8] = {e0v.x,e0v.y,e0v.z,e0v.w,e1v.x,e1v.y,e1v.z,e1v.w};
    #pragma unroll
    for (int i=0;i<8;i++){
      av[i] = fmaf(sv[i], wv, av[i]);
      ae[i] = fmaf(ev[i], we, ae[i]);
    }
  }

  const float bv = b_V[j], be = b_Ev[j];
  const int h = j >> 4;
  #pragma unroll
  for (int i=0;i<8;i++){
    const int el = h8 + i;
    const size_t e = (size_t)e0 + el;
    const int t = tIdx[el];
    const float m   = funmap(segmax[(size_t)t*8 + h]);
    const float den = segsum[(size_t)t*8 + h] + 1e-16f;
    const float a   = expf(scores[e*8 + h] - m) / den;
    const float msg = san(((av[i] + bv) + (ae[i] + be)) * a);
    atomicAdd(&agg[(size_t)t*128 + j], msg);
  }
}

// ---- x_out = agg @ W_O + b_O (r10-proven body, f32-native)
__global__ __launch_bounds__(256) void oproj_v12(const float* __restrict__ agg,
    const float* __restrict__ W, const float* __restrict__ bias,
    float* __restrict__ outx)
{
  __shared__ float AT[128][32];
  const int tid  = threadIdx.x;
  const int base = blockIdx.x * 32;

  for (int idx = tid; idx < 32*128; idx += 256){
    int r = idx >> 7, k = idx & 127;
    AT[k][r] = agg[(size_t)(base + r)*128 + k];
  }
  __syncthreads();

  const int j  = tid & 127;
  const int rb = (tid >> 7) * 16;
  float acc[16];
  #pragma unroll
  for (int i=0;i<16;i++) acc[i] = 0.f;

  for (int k=0;k<128;k++){
    const float w = W[(size_t)k*128 + j];
    const float4 a0 = *reinterpret_cast<const float4*>(&AT[k][rb]);
    const float4 a1 = *reinterpret_cast<const float4*>(&AT[k][rb+4]);
    const float4 a2 = *reinterpret_cast<const float4*>(&AT[k][rb+8]);
    const float4 a3 = *reinterpret_cast<const float4*>(&AT[k][rb+12]);
    const float avv[16] = {a0.x,a0.y,a0.z,a0.w,a1.x,a1.y,a1.z,a1.w,
                           a2.x,a2.y,a2.z,a2.w,a3.x,a3.y,a3.z,a3.w};
    #pragma unroll
    for (int i=0;i<16;i++) acc[i] = fmaf(avv[i], w, acc[i]);
  }

  const float bj = bias[j];
  #pragma unroll
  for (int i=0;i<16;i++)
    outx[(size_t)(base + rb + i)*128 + j] = san(acc[i] + bj);
}

extern "C" void kernel_launch(void* const* d_in, const int* in_sizes, int n_in,
                              void* d_out, int out_size, void* d_ws, size_t ws_size,
                              hipStream_t stream)
{
  (void)in_sizes; (void)n_in; (void)out_size; (void)d_ws; (void)ws_size;
  const float* x    = (const float*)d_in[0];
  const float* ea   = (const float*)d_in[1];
  const int*   eidx = (const int*)d_in[2];
  const float* W_Q  = (const float*)d_in[4];  const float* b_Q  = (const float*)d_in[5];
  const float* W_K  = (const float*)d_in[6];  const float* b_K  = (const float*)d_in[7];
  const float* W_V  = (const float*)d_in[8];  const float* b_V  = (const float*)d_in[9];
  const float* W_Ew = (const float*)d_in[10]; const float* b_Ew = (const float*)d_in[11];
  const float* W_Eb = (const float*)d_in[12]; const float* b_Eb = (const float*)d_in[13];
  const float* W_Ev = (const float*)d_in[14]; const float* b_Ev = (const float*)d_in[15];
  const float* W_O  = (const float*)d_in[16]; const float* b_O  = (const float*)d_in[17];
  const float* W_Eo = (const float*)d_in[18]; const float* b_Eo = (const float*)d_in[19];
  const float* W_A  = (const float*)d_in[20]; const float* b_A  = (const float*)d_in[21];

  float* out_x = (float*)d_out;                 // f32, rows [0, N_NODES)
  float* oute  = out_x + OUT_E_ELEM;            // f32, rows [0, N_EDGES) of output 1

  // scratch inside d_out (f32 geometry proven in r9/r10):
  float*    scores = (float*)d_out;                               // bytes [0, 12.8M)
  unsigned* segmax = (unsigned*)((char*)d_out + SCORES_B);        // [12.8, 16M)
  float*    segsum = (float*)((char*)d_out + SCORES_B + SEG_B);   // [16, 19.2M)
  float*    agg    = oute;                                        // bytes [51.2, 102.4M)

  dim3 blk(256);

  hipMemsetAsync((void*)segmax, 0, 2*SEG_B, stream);
  hipMemsetAsync((void*)agg, 0, AGG_BYTES, stream);

  // scores+segmax for all edges; fused Eo for edges [HALF_E, N_EDGES)
  // (Eo rows [HALF_E,N) = bytes [153.6M, 256M) — disjoint from agg)
  front_mfma_v12<true><<<dim3(N_EDGES/16), blk, 0, stream>>>(x, ea, eidx,
      W_Q, b_Q, W_K, b_K, W_Ew, b_Ew, W_Eb, b_Eb, W_A, b_A, W_Eo, b_Eo,
      scores, segmax, oute, HALF_E);

  seg_sum_v12<<<dim3((N_EDGES*8 + 255)/256), blk, 0, stream>>>(scores, eidx, segmax, segsum);

  messages_v12<<<dim3(N_EDGES/16), blk, 0, stream>>>(x, ea, eidx,
      W_V, b_V, W_Ev, b_Ev, scores, segmax, segsum, agg);

  // x_out (overwrites scores/segmax/segsum — dead by now)
  oproj_v12<<<dim3(N_NODES/32), blk, 0, stream>>>(agg, W_O, b_O, out_x);

  // Eo lower half (overwrites agg region — dead after oproj)
  front_mfma_v12<false><<<dim3(HALF_E/16), blk, 0, stream>>>(x, ea, eidx,
      W_Q, b_Q, W_K, b_K, W_Ew, b_Ew, W_Eb, b_Eb, W_A, b_A, W_Eo, b_Eo,
      nullptr, nullptr, oute, 0);
}